// Round 6
// baseline (623.786 us; speedup 1.0000x reference)
//
#include <hip/hip_runtime.h>
#include <hip/hip_cooperative_groups.h>

namespace cg = cooperative_groups;

#define NN 8192
#define INC 128
#define HC 256          // HEADS*OUT
#define NPB 8           // nodes per group (phase A)
#define NGRP (NN / NPB) // 1024 node groups
#define NB 512          // coop grid: 2 blocks/CU -> co-residency guaranteed
#define SCORE_BLOCKS 1024

// ---------- Phase A: h = x@W+b ; ps/pd = h@att1 halves (one 8-node group) ----------
__device__ __forceinline__ void phaseA_group(
    int grp, int t, const float* __restrict__ x, const float* __restrict__ W,
    const float* __restrict__ bias, const float* __restrict__ att1,
    float* __restrict__ h, float* __restrict__ ps, float* __restrict__ pd,
    float* xs, float* hs) {
  int n0 = grp * NPB;
  ((float4*)xs)[t] = ((const float4*)(x + (size_t)n0 * INC))[t];
  __syncthreads();
  float acc[NPB];
  float b = bias[t];
  #pragma unroll
  for (int n = 0; n < NPB; ++n) acc[n] = b;
  #pragma unroll 4
  for (int d = 0; d < INC; ++d) {
    float w = W[d * HC + t];
    #pragma unroll
    for (int n = 0; n < NPB; ++n) acc[n] += xs[n * INC + d] * w;  // LDS broadcast
  }
  #pragma unroll
  for (int n = 0; n < NPB; ++n) {
    h[((size_t)(n0 + n)) * HC + t] = acc[n];
    hs[n * HC + t] = acc[n];
  }
  __syncthreads();
  int f = t & 63, sel = t >> 6;
  int hh = sel & 1, isdst = sel >> 1;
  const float* a1 = att1 + (isdst ? 128 * 64 : 0) + f;
  float p[NPB];
  #pragma unroll
  for (int n = 0; n < NPB; ++n) p[n] = 0.f;
  #pragma unroll 4
  for (int d = 0; d < 128; ++d) {
    float w = a1[d * 64];
    #pragma unroll
    for (int n = 0; n < NPB; ++n) p[n] += hs[n * HC + hh * 128 + d] * w;
  }
  float* dp = isdst ? pd : ps;
  #pragma unroll
  for (int n = 0; n < NPB; ++n)
    dp[((size_t)(n0 + n)) * 128 + hh * 64 + f] = p[n];
}

// ---------- Phase B: exps = exp(score); per-head sums; CSR offsets ----------
__device__ __forceinline__ void phaseB(
    int bid, int nblocks, int t, const float* __restrict__ ps,
    const float* __restrict__ pd, const int* __restrict__ ei,
    const float* __restrict__ att2, float* __restrict__ exps,
    float* __restrict__ sums, int* __restrict__ offs, int E, float* smem) {
  float* w2 = smem;          // [64]
  float* ssum = smem + 64;   // [2]
  if (t < 64) w2[t] = att2[t];
  if (t < 2) ssum[t] = 0.f;
  __syncthreads();
  int g = t >> 4, sub = t & 15;
  int total = E * 2;
  float runsum = 0.f;   // pair parity (head) fixed per thread: stride is even
  for (int pair = bid * 16 + g; pair < total; pair += nblocks * 16) {
    int hh = pair & 1;
    int e = pair >> 1;
    int s = ei[e], dt = ei[E + e];
    float4 av = *(const float4*)&ps[((size_t)s * 2 + hh) * 64 + sub * 4];
    float4 bv = *(const float4*)&pd[((size_t)dt * 2 + hh) * 64 + sub * 4];
    float vx = av.x + bv.x; vx = vx > 0.f ? vx : 0.01f * vx;
    float vy = av.y + bv.y; vy = vy > 0.f ? vy : 0.01f * vy;
    float vz = av.z + bv.z; vz = vz > 0.f ? vz : 0.01f * vz;
    float vw = av.w + bv.w; vw = vw > 0.f ? vw : 0.01f * vw;
    float sc = vx * w2[sub * 4] + vy * w2[sub * 4 + 1] + vz * w2[sub * 4 + 2] + vw * w2[sub * 4 + 3];
    #pragma unroll
    for (int off = 8; off; off >>= 1) sc += __shfl_down(sc, off, 16);
    if (sub == 0) {
      float ev = __expf(sc);   // non-stable softmax: |sc| = O(10), f32-safe
      exps[pair] = ev;
      runsum += ev;
      if (hh == 0) {           // CSR build (edge list sorted by src)
        if (e == 0) offs[0] = 0;
        else if (ei[e] != ei[e - 1]) offs[ei[e]] = e;
        if (e == E - 1) offs[NN] = E;
      }
    }
  }
  runsum += __shfl_xor(runsum, 32);   // lanes 0<->32, 16<->48 share a head
  int lane = t & 63;
  if (lane == 0 || lane == 16) atomicAdd(&ssum[(t >> 4) & 1], runsum);
  __syncthreads();
  if (t < 2) atomicAdd(&sums[t], ssum[t]);
}

// ---------- Phase C: one node's weighted aggregation ----------
__device__ __forceinline__ void phaseC_node(
    int n, int t, int hh, float inv, const float* __restrict__ h,
    const float* __restrict__ exps, const int* __restrict__ ei,
    const int* __restrict__ offs, float* __restrict__ out, int E, float* l) {
  int lo = offs[n], hi = offs[n + 1];
  float acc = 0.f;
  int e = lo;
  for (; e + 4 <= hi; e += 4) {   // 4 rows in flight
    int d0 = ei[E + e], d1 = ei[E + e + 1], d2 = ei[E + e + 2], d3 = ei[E + e + 3];
    float w0 = exps[2 * e + hh],       w1 = exps[2 * (e + 1) + hh];
    float w2v = exps[2 * (e + 2) + hh], w3 = exps[2 * (e + 3) + hh];
    float h0 = h[(size_t)d0 * HC + t], h1 = h[(size_t)d1 * HC + t];
    float h2 = h[(size_t)d2 * HC + t], h3 = h[(size_t)d3 * HC + t];
    acc += w0 * h0 + w1 * h1 + w2v * h2 + w3 * h3;
  }
  for (; e < hi; ++e)
    acc += exps[2 * e + hh] * h[(size_t)ei[E + e] * HC + t];
  acc *= inv;
  __syncthreads();
  l[t] = acc;
  __syncthreads();
  if (t < 128)
    out[(size_t)n * 128 + t] = 0.5f * (l[t] + l[128 + t]);
}

// ================= cooperative fused kernel =================
__global__ __launch_bounds__(256, 2) void k_fused(
    const float* __restrict__ x, const float* __restrict__ W,
    const float* __restrict__ bias, const float* __restrict__ att1,
    const float* __restrict__ att2, const int* __restrict__ ei,
    float* __restrict__ h, float* __restrict__ ps, float* __restrict__ pd,
    float* __restrict__ exps, float* __restrict__ sums, int* __restrict__ offs,
    float* __restrict__ out, int E) {
  cg::grid_group grid = cg::this_grid();
  __shared__ float smem[NPB * INC + NPB * HC];   // 12 KB, aliased per phase
  int t = threadIdx.x, bid = blockIdx.x;
  if (bid == 0 && t < 2) sums[t] = 0.f;
  for (int grp = bid; grp < NGRP; grp += NB)
    phaseA_group(grp, t, x, W, bias, att1, h, ps, pd, smem, smem + NPB * INC);
  grid.sync();
  phaseB(bid, NB, t, ps, pd, ei, att2, exps, sums, offs, E, smem);
  grid.sync();
  {
    int hh = t >> 7;
    float inv = 1.0f / sums[hh];
    for (int n = bid; n < NN; n += NB)
      phaseC_node(n, t, hh, inv, h, exps, ei, offs, out, E, smem);
  }
}

// ================= fallback: 3 separate kernels =================
__global__ __launch_bounds__(256) void k_h_p_sep(
    const float* __restrict__ x, const float* __restrict__ W,
    const float* __restrict__ bias, const float* __restrict__ att1,
    float* __restrict__ h, float* __restrict__ ps, float* __restrict__ pd,
    float* __restrict__ sums) {
  __shared__ float smem[NPB * INC + NPB * HC];
  if (blockIdx.x == 0 && threadIdx.x < 2) sums[threadIdx.x] = 0.f;
  phaseA_group(blockIdx.x, threadIdx.x, x, W, bias, att1, h, ps, pd,
               smem, smem + NPB * INC);
}

__global__ __launch_bounds__(256) void k_score_sep(
    const float* __restrict__ ps, const float* __restrict__ pd,
    const int* __restrict__ ei, const float* __restrict__ att2,
    float* __restrict__ exps, float* __restrict__ sums,
    int* __restrict__ offs, int E) {
  __shared__ float smem[66];
  phaseB(blockIdx.x, SCORE_BLOCKS, threadIdx.x, ps, pd, ei, att2, exps, sums,
         offs, E, smem);
}

__global__ __launch_bounds__(256) void k_agg_sep(
    const float* __restrict__ h, const float* __restrict__ exps,
    const float* __restrict__ sums, const int* __restrict__ ei,
    const int* __restrict__ offs, float* __restrict__ out, int E) {
  __shared__ float l[HC];
  int t = threadIdx.x, hh = t >> 7;
  float inv = 1.0f / sums[hh];
  phaseC_node(blockIdx.x, t, hh, inv, h, exps, ei, offs, out, E, l);
}

extern "C" void kernel_launch(void* const* d_in, const int* in_sizes, int n_in,
                              void* d_out, int out_size, void* d_ws, size_t ws_size,
                              hipStream_t stream) {
  const float* x    = (const float*)d_in[0];
  // d_in[1] = theta: UNUSED by the reference (edge list precomputed)
  const float* W    = (const float*)d_in[2];
  const float* bias = (const float*)d_in[3];
  const float* att1 = (const float*)d_in[4];
  const float* att2 = (const float*)d_in[5];
  const int* ei = (const int*)d_in[6];
  int E = in_sizes[6] / 2;
  float* out = (float*)d_out;

  float* ws = (float*)d_ws;
  float* h      = ws;                                  // 8 MB
  float* ps     = h  + (size_t)NN * HC;                // 4 MB
  float* pd     = ps + (size_t)NN * 128;               // 4 MB
  float* exps   = pd + (size_t)NN * 128;               // ~2 MB
  float* sums   = exps + (size_t)E * 2;                // 2 f32
  int*   offs   = (int*)(sums + 2);                    // NN+1 ints

  void* args[] = { (void*)&x, (void*)&W, (void*)&bias, (void*)&att1,
                   (void*)&att2, (void*)&ei, (void*)&h, (void*)&ps,
                   (void*)&pd, (void*)&exps, (void*)&sums, (void*)&offs,
                   (void*)&out, (void*)&E };
  hipError_t err = hipLaunchCooperativeKernel((const void*)k_fused, dim3(NB),
                                              dim3(256), args, 0, stream);
  if (err != hipSuccess) {
    // deterministic fallback: identical math via the same device functions
    k_h_p_sep<<<NGRP, 256, 0, stream>>>(x, W, bias, att1, h, ps, pd, sums);
    k_score_sep<<<SCORE_BLOCKS, 256, 0, stream>>>(ps, pd, ei, att2, exps, sums, offs, E);
    k_agg_sep<<<NN, 256, 0, stream>>>(h, exps, sums, ei, offs, out, E);
  }
}

// Round 7
// 431.478 us; speedup vs baseline: 1.4457x; 1.4457x over previous
//
#include <hip/hip_runtime.h>
#include <hip/hip_bf16.h>

#define NN 8192
#define INC 128
#define HC 256          // HEADS*OUT
#define NPB 16          // nodes per block in k_h_p
#define NGRP (NN / NPB) // 512 blocks
#define SCORE_BLOCKS 1024

// K1: h = x@W+b ; ps/pd = h@att1 halves. 16 nodes/block, register-blocked.
__global__ __launch_bounds__(256) void k_h_p(
    const float* __restrict__ x, const float* __restrict__ W,
    const float* __restrict__ bias, const float* __restrict__ att1,
    float* __restrict__ h, float* __restrict__ ps, float* __restrict__ pd,
    float* __restrict__ sums) {
  int t = threadIdx.x;
  int n0 = blockIdx.x * NPB;
  if (blockIdx.x == 0 && t < 2) sums[t] = 0.f;   // zero softmax denominators
  __shared__ float xs[NPB * INC];   // 8 KB
  __shared__ float hs[NPB * HC];    // 16 KB
  // stage x tile: 16 rows * 128 = 2048 floats = 512 float4, coalesced
  {
    const float4* xin = (const float4*)(x + (size_t)n0 * INC);
    ((float4*)xs)[t] = xin[t];
    ((float4*)xs)[t + 256] = xin[t + 256];
  }
  __syncthreads();
  // h: thread t owns column c=t for all 16 nodes
  {
    float acc[NPB];
    float b = bias[t];
    #pragma unroll
    for (int n = 0; n < NPB; ++n) acc[n] = b;
    #pragma unroll 2
    for (int d = 0; d < INC; ++d) {
      float w = W[d * HC + t];
      #pragma unroll
      for (int n = 0; n < NPB; ++n) acc[n] += xs[n * INC + d] * w;  // broadcast
    }
    #pragma unroll
    for (int n = 0; n < NPB; ++n) {
      h[((size_t)(n0 + n)) * HC + t] = acc[n];
      hs[n * HC + t] = acc[n];
    }
  }
  __syncthreads();
  // p: sel = t>>6 -> (isdst, head); f = t&63
  int f = t & 63, sel = t >> 6;
  int hh = sel & 1, isdst = sel >> 1;
  const float* a1 = att1 + (isdst ? 128 * 64 : 0) + f;
  float p[NPB];
  #pragma unroll
  for (int n = 0; n < NPB; ++n) p[n] = 0.f;
  #pragma unroll 2
  for (int d = 0; d < 128; ++d) {
    float w = a1[d * 64];
    #pragma unroll
    for (int n = 0; n < NPB; ++n) p[n] += hs[n * HC + hh * 128 + d] * w;
  }
  float* dp = isdst ? pd : ps;
  #pragma unroll
  for (int n = 0; n < NPB; ++n)
    dp[((size_t)(n0 + n)) * 128 + hh * 64 + f] = p[n];
}

// K2: exps = exp(score); per-head sums (2 atomics/block); CSR offsets.
// Non-stable softmax: |score| = O(10) (xavier weights, unit-normal x) -> f32-safe,
// mathematically identical to max-shifted softmax.
__global__ __launch_bounds__(256) void k_score(
    const float* __restrict__ ps, const float* __restrict__ pd,
    const int* __restrict__ ei, const float* __restrict__ att2,
    float* __restrict__ exps, float* __restrict__ sums,
    int* __restrict__ offs, int E) {
  __shared__ float w2[64];
  __shared__ float ssum[2];
  int t = threadIdx.x;
  if (t < 64) w2[t] = att2[t];
  if (t < 2) ssum[t] = 0.f;
  __syncthreads();
  int g = t >> 4, sub = t & 15;
  int total = E * 2;
  float runsum = 0.f;   // pair parity (head) fixed per thread: stride is even
  for (int pair = blockIdx.x * 16 + g; pair < total; pair += SCORE_BLOCKS * 16) {
    int hh = pair & 1;
    int e = pair >> 1;
    int s = ei[e], dt = ei[E + e];
    float4 av = *(const float4*)&ps[((size_t)s * 2 + hh) * 64 + sub * 4];
    float4 bv = *(const float4*)&pd[((size_t)dt * 2 + hh) * 64 + sub * 4];
    float vx = av.x + bv.x; vx = vx > 0.f ? vx : 0.01f * vx;
    float vy = av.y + bv.y; vy = vy > 0.f ? vy : 0.01f * vy;
    float vz = av.z + bv.z; vz = vz > 0.f ? vz : 0.01f * vz;
    float vw = av.w + bv.w; vw = vw > 0.f ? vw : 0.01f * vw;
    float sc = vx * w2[sub * 4] + vy * w2[sub * 4 + 1] + vz * w2[sub * 4 + 2] + vw * w2[sub * 4 + 3];
    #pragma unroll
    for (int off = 8; off; off >>= 1) sc += __shfl_down(sc, off, 16);
    if (sub == 0) {
      float ev = __expf(sc);
      exps[pair] = ev;
      runsum += ev;
      if (hh == 0) {           // CSR build (edge list sorted by src)
        if (e == 0) offs[0] = 0;
        else if (ei[e] != ei[e - 1]) offs[ei[e]] = e;
        if (e == E - 1) offs[NN] = E;
      }
    }
  }
  runsum += __shfl_xor(runsum, 32);   // lanes 0<->32, 16<->48 share a head
  int lane = t & 63;
  if (lane == 0 || lane == 16) atomicAdd(&ssum[(t >> 4) & 1], runsum);
  __syncthreads();
  if (t < 2) atomicAdd(&sums[t], ssum[t]);
}

// K3: out[n,d] = 0.5 * sum_hh (1/sums[hh]) * sum_{e: src=n} exps[e,hh]*h[dst,hh,d]
// One node per block (8192 blocks -> full latency hiding), 4 rows in flight.
__global__ __launch_bounds__(256) void k_agg(
    const float* __restrict__ h, const float* __restrict__ exps,
    const float* __restrict__ sums, const int* __restrict__ ei,
    const int* __restrict__ offs, float* __restrict__ out, int E) {
  int n = blockIdx.x, t = threadIdx.x;
  int lo = offs[n], hi = offs[n + 1];
  int hh = t >> 7;
  float inv = 1.0f / sums[hh];
  float acc = 0.f;
  int e = lo;
  for (; e + 4 <= hi; e += 4) {
    int d0 = ei[E + e], d1 = ei[E + e + 1], d2 = ei[E + e + 2], d3 = ei[E + e + 3];
    float w0 = exps[2 * e + hh],        w1 = exps[2 * (e + 1) + hh];
    float w2v = exps[2 * (e + 2) + hh], w3 = exps[2 * (e + 3) + hh];
    float h0 = h[(size_t)d0 * HC + t], h1 = h[(size_t)d1 * HC + t];
    float h2 = h[(size_t)d2 * HC + t], h3 = h[(size_t)d3 * HC + t];
    acc += w0 * h0 + w1 * h1 + w2v * h2 + w3 * h3;
  }
  for (; e < hi; ++e)
    acc += exps[2 * e + hh] * h[(size_t)ei[E + e] * HC + t];
  acc *= inv;
  __shared__ float l[HC];
  l[t] = acc;
  __syncthreads();
  if (t < 128)
    out[(size_t)n * 128 + t] = 0.5f * (l[t] + l[128 + t]);
}

extern "C" void kernel_launch(void* const* d_in, const int* in_sizes, int n_in,
                              void* d_out, int out_size, void* d_ws, size_t ws_size,
                              hipStream_t stream) {
  const float* x    = (const float*)d_in[0];
  // d_in[1] = theta: UNUSED by the reference (edge list precomputed)
  const float* W    = (const float*)d_in[2];
  const float* bias = (const float*)d_in[3];
  const float* att1 = (const float*)d_in[4];
  const float* att2 = (const float*)d_in[5];
  const int* ei = (const int*)d_in[6];
  int E = in_sizes[6] / 2;
  float* out = (float*)d_out;

  float* ws = (float*)d_ws;
  float* h      = ws;                                  // 8 MB
  float* ps     = h  + (size_t)NN * HC;                // 4 MB
  float* pd     = ps + (size_t)NN * 128;               // 4 MB
  float* exps   = pd + (size_t)NN * 128;               // ~2 MB
  float* sums   = exps + (size_t)E * 2;                // 2 f32
  int*   offs   = (int*)(sums + 2);                    // NN+1 ints

  k_h_p<<<NGRP, 256, 0, stream>>>(x, W, bias, att1, h, ps, pd, sums);
  k_score<<<SCORE_BLOCKS, 256, 0, stream>>>(ps, pd, ei, att2, exps, sums, offs, E);
  k_agg<<<NN, 256, 0, stream>>>(h, exps, sums, ei, offs, out, E);
}

// Round 8
// 406.766 us; speedup vs baseline: 1.5335x; 1.0608x over previous
//
#include <hip/hip_runtime.h>
#include <hip/hip_bf16.h>

#define NN 8192
#define INC 128
#define HC 256          // HEADS*OUT
#define NPB 16          // nodes per block in k_h_p
#define NGRP (NN / NPB) // 512 blocks
#define SCALE_BLOCKS 512

// K1: h = x@W+b ; ps/pd = h@att1 halves (16 nodes/block, register-blocked);
// also builds CSR row offsets from the src-sorted edge list.
__global__ __launch_bounds__(256) void k_h_p(
    const float* __restrict__ x, const float* __restrict__ W,
    const float* __restrict__ bias, const float* __restrict__ att1,
    const int* __restrict__ ei, float* __restrict__ h,
    float* __restrict__ ps, float* __restrict__ pd,
    int* __restrict__ offs, int E) {
  int t = threadIdx.x;
  int n0 = blockIdx.x * NPB;
  // CSR build (independent of matmul; overlaps with staging)
  for (int e = blockIdx.x * 256 + t; e < E; e += NGRP * 256) {
    if (e == 0) offs[0] = 0;
    else { int s1 = ei[e]; if (s1 != ei[e - 1]) offs[s1] = e; }
    if (e == E - 1) offs[NN] = E;
  }
  __shared__ float xs[NPB * INC];   // 8 KB
  __shared__ float hs[NPB * HC];    // 16 KB
  {
    const float4* xin = (const float4*)(x + (size_t)n0 * INC);
    ((float4*)xs)[t] = xin[t];
    ((float4*)xs)[t + 256] = xin[t + 256];
  }
  __syncthreads();
  {
    float acc[NPB];
    float b = bias[t];
    #pragma unroll
    for (int n = 0; n < NPB; ++n) acc[n] = b;
    #pragma unroll 2
    for (int d = 0; d < INC; ++d) {
      float w = W[d * HC + t];
      #pragma unroll
      for (int n = 0; n < NPB; ++n) acc[n] += xs[n * INC + d] * w;  // broadcast
    }
    #pragma unroll
    for (int n = 0; n < NPB; ++n) {
      h[((size_t)(n0 + n)) * HC + t] = acc[n];
      hs[n * HC + t] = acc[n];
    }
  }
  __syncthreads();
  int f = t & 63, sel = t >> 6;
  int hh = sel & 1, isdst = sel >> 1;
  const float* a1 = att1 + (isdst ? 128 * 64 : 0) + f;
  float p[NPB];
  #pragma unroll
  for (int n = 0; n < NPB; ++n) p[n] = 0.f;
  #pragma unroll 2
  for (int d = 0; d < 128; ++d) {
    float w = a1[d * 64];
    #pragma unroll
    for (int n = 0; n < NPB; ++n) p[n] += hs[n * HC + hh * 128 + d] * w;
  }
  float* dp = isdst ? pd : ps;
  #pragma unroll
  for (int n = 0; n < NPB; ++n)
    dp[((size_t)(n0 + n)) * 128 + hh * 64 + f] = p[n];
}

// K2: fused score+exp+aggregate for node n (one block):
//   raw[n][hh*128+d] = sum_{e: src=n} exp(score(e,hh)) * h[dst_e][hh*128+d]
//   part[n][hh]      = sum_{e: src=n} exp(score(e,hh))
// ps[n] lives in LDS (score gather is pd-only). Wave w handles edges lo+w, lo+w+4,...
// Lane mapping: head = lane>>5, j = lane&31 (2 score elems / 4 h cols per lane).
// Non-stable softmax: |score| = O(10) -> exp is f32-safe, identical result.
__global__ __launch_bounds__(256) void k_agg(
    const float* __restrict__ h, const float* __restrict__ ps,
    const float* __restrict__ pd, const int* __restrict__ ei,
    const float* __restrict__ att2, const int* __restrict__ offs,
    float* __restrict__ raw, float* __restrict__ part, int E) {
  int n = blockIdx.x, t = threadIdx.x;
  __shared__ float psl[128];
  __shared__ float w2l[64];
  __shared__ float red[4 * HC];   // per-wave accumulators
  __shared__ float rs[4][2];      // per-wave head sums
  if (t < 128) psl[t] = ps[(size_t)n * 128 + t];
  if (t < 64) w2l[t] = att2[t];
  __syncthreads();
  int wid = t >> 6, lane = t & 63;
  int head = lane >> 5, j = lane & 31;
  int lo = offs[n], hi = offs[n + 1];
  float pa = psl[head * 64 + j * 2], pb = psl[head * 64 + j * 2 + 1];
  float wa = w2l[j * 2], wb = w2l[j * 2 + 1];
  float4 acc = {0.f, 0.f, 0.f, 0.f};
  float rsum = 0.f;
  for (int e = lo + wid; e < hi; e += 4) {
    int dst = ei[E + e];                       // wave-uniform
    float4 h4 = *(const float4*)&h[(size_t)dst * HC + lane * 4];
    float2 pdv = *(const float2*)&pd[(size_t)dst * 128 + head * 64 + j * 2];
    float v0 = pa + pdv.x; v0 = v0 > 0.f ? v0 : 0.01f * v0;
    float v1 = pb + pdv.y; v1 = v1 > 0.f ? v1 : 0.01f * v1;
    float sc = v0 * wa + v1 * wb;
    sc += __shfl_xor(sc, 1);  sc += __shfl_xor(sc, 2);  sc += __shfl_xor(sc, 4);
    sc += __shfl_xor(sc, 8);  sc += __shfl_xor(sc, 16);  // full sum within 32-half
    float ev = __expf(sc);
    if (j == 0) rsum += ev;
    acc.x += ev * h4.x; acc.y += ev * h4.y; acc.z += ev * h4.z; acc.w += ev * h4.w;
  }
  ((float4*)red)[wid * 64 + lane] = acc;       // red[wid*256 + col]
  if (j == 0) rs[wid][head] = rsum;
  __syncthreads();
  float tot = red[t] + red[HC + t] + red[2 * HC + t] + red[3 * HC + t];
  raw[(size_t)n * HC + t] = tot;
  if (t < 2)
    part[n * 2 + t] = rs[0][t] + rs[1][t] + rs[2][t] + rs[3][t];
}

// K3: reduce part[8192][2] -> per-head sums (every block, L2-hot), then
//   out[n][d] = 0.5*(raw[n][d]*inv0 + raw[n][128+d]*inv1)
__global__ __launch_bounds__(256) void k_scale(
    const float* __restrict__ raw, const float* __restrict__ part,
    float* __restrict__ out) {
  int t = threadIdx.x;
  float s0 = 0.f, s1 = 0.f;
  #pragma unroll 4
  for (int k = 0; k < 32; ++k) {
    float2 p = ((const float2*)part)[t + 256 * k];
    s0 += p.x; s1 += p.y;
  }
  #pragma unroll
  for (int off = 1; off <= 32; off <<= 1) {
    s0 += __shfl_xor(s0, off);
    s1 += __shfl_xor(s1, off);
  }
  __shared__ float ws0[4], ws1[4];
  if ((t & 63) == 0) { ws0[t >> 6] = s0; ws1[t >> 6] = s1; }
  __syncthreads();
  float inv0 = 1.f / (ws0[0] + ws0[1] + ws0[2] + ws0[3]);
  float inv1 = 1.f / (ws1[0] + ws1[1] + ws1[2] + ws1[3]);
  const float4* r4 = (const float4*)raw;
  float4* o4 = (float4*)out;
  int idx = blockIdx.x * 256 + t;
  #pragma unroll
  for (int rep = 0; rep < 2; ++rep, idx += SCALE_BLOCKS * 256) {
    int nn = idx >> 5, c4 = idx & 31;          // 32 float4 per 128-col out row
    float4 a = r4[nn * 64 + c4];               // head0 cols
    float4 b = r4[nn * 64 + 32 + c4];          // head1 cols
    float4 o;
    o.x = 0.5f * (a.x * inv0 + b.x * inv1);
    o.y = 0.5f * (a.y * inv0 + b.y * inv1);
    o.z = 0.5f * (a.z * inv0 + b.z * inv1);
    o.w = 0.5f * (a.w * inv0 + b.w * inv1);
    o4[idx] = o;
  }
}

extern "C" void kernel_launch(void* const* d_in, const int* in_sizes, int n_in,
                              void* d_out, int out_size, void* d_ws, size_t ws_size,
                              hipStream_t stream) {
  const float* x    = (const float*)d_in[0];
  // d_in[1] = theta: UNUSED by the reference (edge list precomputed)
  const float* W    = (const float*)d_in[2];
  const float* bias = (const float*)d_in[3];
  const float* att1 = (const float*)d_in[4];
  const float* att2 = (const float*)d_in[5];
  const int* ei = (const int*)d_in[6];
  int E = in_sizes[6] / 2;
  float* out = (float*)d_out;

  float* ws = (float*)d_ws;
  float* h    = ws;                         // 8 MB
  float* ps   = h  + (size_t)NN * HC;       // 4 MB
  float* pd   = ps + (size_t)NN * 128;      // 4 MB
  float* raw  = pd + (size_t)NN * 128;      // 8 MB
  float* part = raw + (size_t)NN * HC;      // 64 KB
  int*   offs = (int*)(part + (size_t)NN * 2);  // NN+1 ints

  k_h_p<<<NGRP, 256, 0, stream>>>(x, W, bias, att1, ei, h, ps, pd, offs, E);
  k_agg<<<NN, 256, 0, stream>>>(h, ps, pd, ei, att2, offs, raw, part, E);
  k_scale<<<SCALE_BLOCKS, 256, 0, stream>>>(raw, part, out);
}